// Round 14
// baseline (272.018 us; speedup 1.0000x reference)
//
#include <hip/hip_runtime.h>

#define HEADS 4
#define DH 64
#define NHID 256   // HEADS*DH
#define KIN 256
#define NEG_SLOPE 0.2f
#define CAP 128    // bucket capacity; deg ~ Poisson(16), P(deg>128) ~ 1e-60
#define EPB 2048   // edges per fill block (256 threads x 8)

typedef __attribute__((ext_vector_type(8))) short short8;
typedef __attribute__((ext_vector_type(4))) float f32x4;

__device__ inline float bf2f(unsigned short u) {
  union { unsigned int i; float f; } v; v.i = ((unsigned int)u) << 16; return v.f;
}
__device__ inline unsigned short f2bf(float f) {
  union { float f; unsigned int i; } v; v.f = f;
  unsigned int r = v.i + 0x7FFF + ((v.i >> 16) & 1);  // RNE
  return (unsigned short)(r >> 16);
}

// -------- k_cvtW: W transpose+convert to bf16; also zero-inits deg (kills memset node)
__global__ void k_cvtW(const float* __restrict__ W, unsigned short* __restrict__ Wt,
                       int* __restrict__ deg, int M) {
  int n = blockIdx.x, k = threadIdx.x;
  Wt[n * 256 + k] = f2bf(W[k * 256 + n]);
  for (int i = blockIdx.x * 256 + threadIdx.x; i < M; i += 256 * 256) deg[i] = 0;
}

// -------- k_fillgemm: fused fill + projection, B-from-L2 variant.
// Gemm path: A (64x256) staged once to LDS (XOR-swizzled, 2-pass to bound VGPR);
// B read per-wave directly global->VGPR (Wt is L2-resident) -> NO B staging, NO
// K-loop barriers, LDS 32KB. (256,3): 3 blocks/CU (+50% TLP vs round 13).
__global__ __launch_bounds__(256, 3) void k_fillgemm(
    const float* __restrict__ feat, const unsigned short* __restrict__ Wt,
    const float* __restrict__ al, const float* __restrict__ ar,
    unsigned short* __restrict__ ftb, float* __restrict__ el,
    float* __restrict__ er, int M,
    const int* __restrict__ src, const int* __restrict__ dst,
    int* __restrict__ deg, int* __restrict__ bucket, int E)
{
  __shared__ unsigned short As[64 * 256];       // 32 KB: full A tile, bf16
  const int t = threadIdx.x;
  const int b = blockIdx.x;
  const int q = b / 3, rmd = b % 3;

  if (rmd == 0) {
    // ---------------- fill path: edges [q*EPB, q*EPB+EPB) ----------------
    int e0 = q * EPB + t;
    #pragma unroll
    for (int j = 0; j < 8; ++j) {
      int e = e0 + j * 256;
      if (e < E) {
        int d = __builtin_nontemporal_load(dst + e);
        int s = __builtin_nontemporal_load(src + e);
        int p = atomicAdd(&deg[d], 1);
        bucket[(size_t)d * CAP + p] = s;
      }
    }
    return;
  }

  // ---------------- gemm path: block gi = b - q - 1 ----------------
  const int gi = b - q - 1;
  const int lane = t & 63;
  const int w = t >> 6;                 // wave index == head == col-block
  const int row0 = gi * 64;

  f32x4 acc[4][4] = {};

  // A prologue: 2 passes x 4 chunks (32B each, NT loads) -> cvt -> swizzled ds_write.
  // Peak live: 8 float4 = 32 VGPR per pass.
  #pragma unroll
  for (int p = 0; p < 2; ++p) {
    f32x4 av0[4], av1[4];
    #pragma unroll
    for (int j = 0; j < 4; ++j) {
      int g = (p * 4 + j) * 256 + t;
      int r = g >> 5, c = g & 31;
      const f32x4* ga = (const f32x4*)(feat + (size_t)min(row0 + r, M - 1) * KIN + c * 8);
      av0[j] = __builtin_nontemporal_load(ga);
      av1[j] = __builtin_nontemporal_load(ga + 1);
    }
    #pragma unroll
    for (int j = 0; j < 4; ++j) {
      int g = (p * 4 + j) * 256 + t;
      int r = g >> 5, c = g & 31;
      short8 pk;
      pk[0] = (short)f2bf(av0[j][0]); pk[1] = (short)f2bf(av0[j][1]);
      pk[2] = (short)f2bf(av0[j][2]); pk[3] = (short)f2bf(av0[j][3]);
      pk[4] = (short)f2bf(av1[j][0]); pk[5] = (short)f2bf(av1[j][1]);
      pk[6] = (short)f2bf(av1[j][2]); pk[7] = (short)f2bf(av1[j][3]);
      *(short8*)((char*)As + r * 512 + ((c ^ (r & 7)) * 16)) = pk;
    }
  }
  __syncthreads();   // the ONLY barrier: As read-only below

  const int i = lane & 15, kc = lane >> 4;
  for (int kt = 0; kt < 8; ++kt) {
    short8 af[4], bf[4];
    // B directly from global (L2-hit): row nr, k-cols kt*32 + kc*8 .. +8
    #pragma unroll
    for (int n = 0; n < 4; ++n) {
      int nr = w * 64 + n * 16 + i;
      bf[n] = *(const short8*)(Wt + nr * 256 + kt * 32 + kc * 8);
    }
    #pragma unroll
    for (int m = 0; m < 4; ++m) {
      int r = m * 16 + i;
      int c = kt * 4 + kc;
      af[m] = *(const short8*)((const char*)As + r * 512 + ((c ^ (r & 7)) * 16));
    }
    #pragma unroll
    for (int m = 0; m < 4; ++m)
      #pragma unroll
      for (int n = 0; n < 4; ++n)
        acc[m][n] = __builtin_amdgcn_mfma_f32_16x16x32_bf16(af[m], bf[n], acc[m][n], 0, 0, 0);
  }

  // epilogue: C/D layout col=lane&15, row=(lane>>4)*4+reg  [m89-verified]
  const int ci = lane & 15, rg = lane >> 4;
  #pragma unroll
  for (int m = 0; m < 4; ++m) {
    #pragma unroll
    for (int r = 0; r < 4; ++r) {
      int grow = row0 + m * 16 + rg * 4 + r;
      if (grow < M) {
        unsigned short* fp = ftb + (size_t)grow * NHID + w * 64;
        #pragma unroll
        for (int n = 0; n < 4; ++n) fp[n * 16 + ci] = f2bf(acc[m][n][r]);
      }
    }
  }
  float alv[4], arv[4];
  #pragma unroll
  for (int n = 0; n < 4; ++n) {
    alv[n] = al[w * DH + n * 16 + ci];
    arv[n] = ar[w * DH + n * 16 + ci];
  }
  #pragma unroll
  for (int m = 0; m < 4; ++m) {
    #pragma unroll
    for (int r = 0; r < 4; ++r) {
      float pl = 0.f, pr = 0.f;
      #pragma unroll
      for (int n = 0; n < 4; ++n) {
        pl += acc[m][n][r] * alv[n];
        pr += acc[m][n][r] * arv[n];
      }
      pl += __shfl_xor(pl, 1); pl += __shfl_xor(pl, 2);
      pl += __shfl_xor(pl, 4); pl += __shfl_xor(pl, 8);
      pr += __shfl_xor(pr, 1); pr += __shfl_xor(pr, 2);
      pr += __shfl_xor(pr, 4); pr += __shfl_xor(pr, 8);
      if (ci == 0) {
        int grow = row0 + m * 16 + rg * 4 + r;
        if (grow < M) { el[grow * HEADS + w] = pl; er[grow * HEADS + w] = pr; }
      }
    }
  }
}

// ---------------- Aggregation: wave per node, quarter-wave per edge ----------------
// Round-11 exact form. Serves 819 MB logical in ~136 us = 6.0 TB/s effective
// -- at the memory wall. Frozen.
__global__ __launch_bounds__(256) void k_aggr(
    const unsigned short* __restrict__ ftb, const float* __restrict__ el,
    const float* __restrict__ er, const int* __restrict__ deg,
    const int* __restrict__ bucket, float* __restrict__ out, int N)
{
  int n = blockIdx.x * 4 + (threadIdx.x >> 6);
  int lane = threadIdx.x & 63;
  if (n >= N) return;
  int q  = lane >> 4;          // edge slot 0..3
  int ql = lane & 15;          // dims ql*16 .. ql*16+15
  int hh = ql >> 2;            // head of my dims
  int start = n * CAP;
  int end = start + deg[n];
  const short8* ft8 = (const short8*)ftb;
  float acc[16] = {};
  float ws = 0.f;
  if (end > start) {
    float erh = er[n * HEADS + hh];
    int last = end - 1;
    int eA = start + q;
    int eB = eA + 4;
    int sB = bucket[min(eB, last)];
    {
      int sA = bucket[min(eA, last)];
      float lxA = el[sA * 4 + hh];
      short8 fa0 = ft8[(size_t)sA * 32 + ql * 2];
      short8 fa1 = ft8[(size_t)sA * 32 + ql * 2 + 1];
      for (int e0 = start; e0 < end; e0 += 4) {
        int sC = bucket[min(e0 + 8 + q, last)];
        float lxB = el[sB * 4 + hh];
        short8 fb0 = ft8[(size_t)sB * 32 + ql * 2];
        short8 fb1 = ft8[(size_t)sB * 32 + ql * 2 + 1];
        bool v = (e0 + q) < end;
        float x = lxA + erh;
        x = x > 0.f ? x : NEG_SLOPE * x;
        float ex = v ? __expf(x) : 0.f;
        ws += ex;
        #pragma unroll
        for (int j = 0; j < 8; ++j) acc[j]     += ex * bf2f((unsigned short)fa0[j]);
        #pragma unroll
        for (int j = 0; j < 8; ++j) acc[j + 8] += ex * bf2f((unsigned short)fa1[j]);
        sB = sC; lxA = lxB; fa0 = fb0; fa1 = fb1;
      }
    }
  }
  ws += __shfl_xor(ws, 16); ws += __shfl_xor(ws, 32);
  #pragma unroll
  for (int j = 0; j < 16; ++j) {
    acc[j] += __shfl_xor(acc[j], 16);
    acc[j] += __shfl_xor(acc[j], 32);
  }
  if (q == 0) {
    float inv = (end > start) ? 1.f / ws : 0.f;
    float* op = out + (size_t)n * NHID + ql * 16;
    #pragma unroll
    for (int j4 = 0; j4 < 4; ++j4)
      *(float4*)(op + j4 * 4) = make_float4(acc[j4 * 4] * inv, acc[j4 * 4 + 1] * inv,
                                            acc[j4 * 4 + 2] * inv, acc[j4 * 4 + 3] * inv);
  }
}

// ---------------- launch ----------------
extern "C" void kernel_launch(void* const* d_in, const int* in_sizes, int n_in,
                              void* d_out, int out_size, void* d_ws, size_t ws_size,
                              hipStream_t stream)
{
  const float* feat = (const float*)d_in[0];
  const float* W    = (const float*)d_in[1];
  const float* al   = (const float*)d_in[2];
  const float* ar   = (const float*)d_in[3];
  const int*   src  = (const int*)d_in[4];
  const int*   dst  = (const int*)d_in[5];
  const int M = in_sizes[0] / KIN;   // 100000
  const int E = in_sizes[4];         // 1600000
  float* out = (float*)d_out;

  char* base = (char*)d_ws;
  size_t off = 0;
  auto alloc = [&](size_t b) { char* p = base + off; off = (off + b + 255) & ~(size_t)255; return p; };
  unsigned short* ftb = (unsigned short*)alloc((size_t)M * NHID * sizeof(unsigned short)); // 51.2 MB
  unsigned short* Wt  = (unsigned short*)alloc(256 * 256 * sizeof(unsigned short));
  float* el     = (float*)alloc((size_t)M * HEADS * sizeof(float));
  float* er     = (float*)alloc((size_t)M * HEADS * sizeof(float));
  int*   deg    = (int*)alloc((size_t)M * sizeof(int));
  int*   bucket = (int*)alloc((size_t)M * CAP * sizeof(int));   // 51.2 MB
  (void)ws_size; (void)n_in; (void)out_size;

  k_cvtW<<<256, 256, 0, stream>>>(W, Wt, deg, M);
  int nF = (E + EPB - 1) / EPB;
  int nG = (M + 63) / 64;
  k_fillgemm<<<nF + nG, 256, 0, stream>>>(feat, Wt, al, ar, ftb, el, er, M,
                                          src, dst, deg, bucket, E);
  k_aggr<<<(M + 3) / 4, 256, 0, stream>>>(ftb, el, er, deg, bucket, out, M);
}

// Round 15
// 270.732 us; speedup vs baseline: 1.0048x; 1.0048x over previous
//
#include <hip/hip_runtime.h>

#define HEADS 4
#define DH 64
#define NHID 256   // HEADS*DH
#define KIN 256
#define NEG_SLOPE 0.2f
#define CAP 128    // bucket capacity; deg ~ Poisson(16), P(deg>128) ~ 1e-60
#define EPB 2048   // edges per fill block (256 threads x 8)

typedef __attribute__((ext_vector_type(8))) short short8;
typedef __attribute__((ext_vector_type(4))) float f32x4;

__device__ inline float bf2f(unsigned short u) {
  union { unsigned int i; float f; } v; v.i = ((unsigned int)u) << 16; return v.f;
}
__device__ inline unsigned short f2bf(float f) {
  union { float f; unsigned int i; } v; v.f = f;
  unsigned int r = v.i + 0x7FFF + ((v.i >> 16) & 1);  // RNE
  return (unsigned short)(r >> 16);
}

// -------- k_cvtW: W transpose+convert to bf16; also zero-inits deg (kills memset node)
__global__ void k_cvtW(const float* __restrict__ W, unsigned short* __restrict__ Wt,
                       int* __restrict__ deg, int M) {
  int n = blockIdx.x, k = threadIdx.x;
  Wt[n * 256 + k] = f2bf(W[k * 256 + n]);
  for (int i = blockIdx.x * 256 + threadIdx.x; i < M; i += 256 * 256) deg[i] = 0;
}

// -------- k_fillgemm: fused fill + projection, B-from-L2 variant.
// Gemm path: A (64x256) staged once to LDS (XOR-swizzled); B read per-wave
// directly global->VGPR (Wt L2-resident) -> no B staging, no K-loop barriers.
// (256,2): VGPR cap 256 -- the (256,3) cap of ~170 forced spills (round 14,
// -18us): the unrolled barrier-free K-loop wants ~128 VGPR of B in flight.
__global__ __launch_bounds__(256, 2) void k_fillgemm(
    const float* __restrict__ feat, const unsigned short* __restrict__ Wt,
    const float* __restrict__ al, const float* __restrict__ ar,
    unsigned short* __restrict__ ftb, float* __restrict__ el,
    float* __restrict__ er, int M,
    const int* __restrict__ src, const int* __restrict__ dst,
    int* __restrict__ deg, int* __restrict__ bucket, int E)
{
  __shared__ unsigned short As[64 * 256];       // 32 KB: full A tile, bf16
  const int t = threadIdx.x;
  const int b = blockIdx.x;
  const int q = b / 3, rmd = b % 3;

  if (rmd == 0) {
    // ---------------- fill path: edges [q*EPB, q*EPB+EPB) ----------------
    int e0 = q * EPB + t;
    #pragma unroll
    for (int j = 0; j < 8; ++j) {
      int e = e0 + j * 256;
      if (e < E) {
        int d = __builtin_nontemporal_load(dst + e);
        int s = __builtin_nontemporal_load(src + e);
        int p = atomicAdd(&deg[d], 1);
        bucket[(size_t)d * CAP + p] = s;
      }
    }
    return;
  }

  // ---------------- gemm path: block gi = b - q - 1 ----------------
  const int gi = b - q - 1;
  const int lane = t & 63;
  const int w = t >> 6;                 // wave index == head == col-block
  const int row0 = gi * 64;

  f32x4 acc[4][4] = {};

  // A prologue: 2 passes x 4 chunks (32B each, NT loads) -> cvt -> swizzled ds_write.
  #pragma unroll
  for (int p = 0; p < 2; ++p) {
    f32x4 av0[4], av1[4];
    #pragma unroll
    for (int j = 0; j < 4; ++j) {
      int g = (p * 4 + j) * 256 + t;
      int r = g >> 5, c = g & 31;
      const f32x4* ga = (const f32x4*)(feat + (size_t)min(row0 + r, M - 1) * KIN + c * 8);
      av0[j] = __builtin_nontemporal_load(ga);
      av1[j] = __builtin_nontemporal_load(ga + 1);
    }
    #pragma unroll
    for (int j = 0; j < 4; ++j) {
      int g = (p * 4 + j) * 256 + t;
      int r = g >> 5, c = g & 31;
      short8 pk;
      pk[0] = (short)f2bf(av0[j][0]); pk[1] = (short)f2bf(av0[j][1]);
      pk[2] = (short)f2bf(av0[j][2]); pk[3] = (short)f2bf(av0[j][3]);
      pk[4] = (short)f2bf(av1[j][0]); pk[5] = (short)f2bf(av1[j][1]);
      pk[6] = (short)f2bf(av1[j][2]); pk[7] = (short)f2bf(av1[j][3]);
      *(short8*)((char*)As + r * 512 + ((c ^ (r & 7)) * 16)) = pk;
    }
  }
  __syncthreads();   // the ONLY barrier: As read-only below

  const int i = lane & 15, kc = lane >> 4;
  for (int kt = 0; kt < 8; ++kt) {
    short8 af[4], bf[4];
    // B directly from global (L2-hit): row nr, k-cols kt*32 + kc*8 .. +8
    #pragma unroll
    for (int n = 0; n < 4; ++n) {
      int nr = w * 64 + n * 16 + i;
      bf[n] = *(const short8*)(Wt + nr * 256 + kt * 32 + kc * 8);
    }
    #pragma unroll
    for (int m = 0; m < 4; ++m) {
      int r = m * 16 + i;
      int c = kt * 4 + kc;
      af[m] = *(const short8*)((const char*)As + r * 512 + ((c ^ (r & 7)) * 16));
    }
    #pragma unroll
    for (int m = 0; m < 4; ++m)
      #pragma unroll
      for (int n = 0; n < 4; ++n)
        acc[m][n] = __builtin_amdgcn_mfma_f32_16x16x32_bf16(af[m], bf[n], acc[m][n], 0, 0, 0);
  }

  // epilogue: C/D layout col=lane&15, row=(lane>>4)*4+reg  [m89-verified]
  const int ci = lane & 15, rg = lane >> 4;
  #pragma unroll
  for (int m = 0; m < 4; ++m) {
    #pragma unroll
    for (int r = 0; r < 4; ++r) {
      int grow = row0 + m * 16 + rg * 4 + r;
      if (grow < M) {
        unsigned short* fp = ftb + (size_t)grow * NHID + w * 64;
        #pragma unroll
        for (int n = 0; n < 4; ++n) fp[n * 16 + ci] = f2bf(acc[m][n][r]);
      }
    }
  }
  float alv[4], arv[4];
  #pragma unroll
  for (int n = 0; n < 4; ++n) {
    alv[n] = al[w * DH + n * 16 + ci];
    arv[n] = ar[w * DH + n * 16 + ci];
  }
  #pragma unroll
  for (int m = 0; m < 4; ++m) {
    #pragma unroll
    for (int r = 0; r < 4; ++r) {
      float pl = 0.f, pr = 0.f;
      #pragma unroll
      for (int n = 0; n < 4; ++n) {
        pl += acc[m][n][r] * alv[n];
        pr += acc[m][n][r] * arv[n];
      }
      pl += __shfl_xor(pl, 1); pl += __shfl_xor(pl, 2);
      pl += __shfl_xor(pl, 4); pl += __shfl_xor(pl, 8);
      pr += __shfl_xor(pr, 1); pr += __shfl_xor(pr, 2);
      pr += __shfl_xor(pr, 4); pr += __shfl_xor(pr, 8);
      if (ci == 0) {
        int grow = row0 + m * 16 + rg * 4 + r;
        if (grow < M) { el[grow * HEADS + w] = pl; er[grow * HEADS + w] = pr; }
      }
    }
  }
}

// ---------------- Aggregation: wave per node, quarter-wave per edge ----------------
// Round-11 exact form. Serves 819 MB logical in ~136 us = 6.0 TB/s effective
// -- at the memory wall. Frozen.
__global__ __launch_bounds__(256) void k_aggr(
    const unsigned short* __restrict__ ftb, const float* __restrict__ el,
    const float* __restrict__ er, const int* __restrict__ deg,
    const int* __restrict__ bucket, float* __restrict__ out, int N)
{
  int n = blockIdx.x * 4 + (threadIdx.x >> 6);
  int lane = threadIdx.x & 63;
  if (n >= N) return;
  int q  = lane >> 4;          // edge slot 0..3
  int ql = lane & 15;          // dims ql*16 .. ql*16+15
  int hh = ql >> 2;            // head of my dims
  int start = n * CAP;
  int end = start + deg[n];
  const short8* ft8 = (const short8*)ftb;
  float acc[16] = {};
  float ws = 0.f;
  if (end > start) {
    float erh = er[n * HEADS + hh];
    int last = end - 1;
    int eA = start + q;
    int eB = eA + 4;
    int sB = bucket[min(eB, last)];
    {
      int sA = bucket[min(eA, last)];
      float lxA = el[sA * 4 + hh];
      short8 fa0 = ft8[(size_t)sA * 32 + ql * 2];
      short8 fa1 = ft8[(size_t)sA * 32 + ql * 2 + 1];
      for (int e0 = start; e0 < end; e0 += 4) {
        int sC = bucket[min(e0 + 8 + q, last)];
        float lxB = el[sB * 4 + hh];
        short8 fb0 = ft8[(size_t)sB * 32 + ql * 2];
        short8 fb1 = ft8[(size_t)sB * 32 + ql * 2 + 1];
        bool v = (e0 + q) < end;
        float x = lxA + erh;
        x = x > 0.f ? x : NEG_SLOPE * x;
        float ex = v ? __expf(x) : 0.f;
        ws += ex;
        #pragma unroll
        for (int j = 0; j < 8; ++j) acc[j]     += ex * bf2f((unsigned short)fa0[j]);
        #pragma unroll
        for (int j = 0; j < 8; ++j) acc[j + 8] += ex * bf2f((unsigned short)fa1[j]);
        sB = sC; lxA = lxB; fa0 = fb0; fa1 = fb1;
      }
    }
  }
  ws += __shfl_xor(ws, 16); ws += __shfl_xor(ws, 32);
  #pragma unroll
  for (int j = 0; j < 16; ++j) {
    acc[j] += __shfl_xor(acc[j], 16);
    acc[j] += __shfl_xor(acc[j], 32);
  }
  if (q == 0) {
    float inv = (end > start) ? 1.f / ws : 0.f;
    float* op = out + (size_t)n * NHID + ql * 16;
    #pragma unroll
    for (int j4 = 0; j4 < 4; ++j4)
      *(float4*)(op + j4 * 4) = make_float4(acc[j4 * 4] * inv, acc[j4 * 4 + 1] * inv,
                                            acc[j4 * 4 + 2] * inv, acc[j4 * 4 + 3] * inv);
  }
}

// ---------------- launch ----------------
extern "C" void kernel_launch(void* const* d_in, const int* in_sizes, int n_in,
                              void* d_out, int out_size, void* d_ws, size_t ws_size,
                              hipStream_t stream)
{
  const float* feat = (const float*)d_in[0];
  const float* W    = (const float*)d_in[1];
  const float* al   = (const float*)d_in[2];
  const float* ar   = (const float*)d_in[3];
  const int*   src  = (const int*)d_in[4];
  const int*   dst  = (const int*)d_in[5];
  const int M = in_sizes[0] / KIN;   // 100000
  const int E = in_sizes[4];         // 1600000
  float* out = (float*)d_out;

  char* base = (char*)d_ws;
  size_t off = 0;
  auto alloc = [&](size_t b) { char* p = base + off; off = (off + b + 255) & ~(size_t)255; return p; };
  unsigned short* ftb = (unsigned short*)alloc((size_t)M * NHID * sizeof(unsigned short)); // 51.2 MB
  unsigned short* Wt  = (unsigned short*)alloc(256 * 256 * sizeof(unsigned short));
  float* el     = (float*)alloc((size_t)M * HEADS * sizeof(float));
  float* er     = (float*)alloc((size_t)M * HEADS * sizeof(float));
  int*   deg    = (int*)alloc((size_t)M * sizeof(int));
  int*   bucket = (int*)alloc((size_t)M * CAP * sizeof(int));   // 51.2 MB
  (void)ws_size; (void)n_in; (void)out_size;

  k_cvtW<<<256, 256, 0, stream>>>(W, Wt, deg, M);
  int nF = (E + EPB - 1) / EPB;
  int nG = (M + 63) / 64;
  k_fillgemm<<<nF + nG, 256, 0, stream>>>(feat, Wt, al, ar, ftb, el, er, M,
                                          src, dst, deg, bucket, E);
  k_aggr<<<(M + 3) / 4, 256, 0, stream>>>(ftb, el, er, deg, bucket, out, M);
}

// Round 16
// 253.263 us; speedup vs baseline: 1.0741x; 1.0690x over previous
//
#include <hip/hip_runtime.h>

#define HEADS 4
#define DH 64
#define NHID 256   // HEADS*DH
#define KIN 256
#define NEG_SLOPE 0.2f
#define CAP 128    // bucket capacity; deg ~ Poisson(16), P(deg>128) ~ 1e-60
#define EPB 2048   // edges per fill block (256 threads x 8)

typedef __attribute__((ext_vector_type(8))) short short8;
typedef __attribute__((ext_vector_type(4))) float f32x4;

__device__ inline float bf2f(unsigned short u) {
  union { unsigned int i; float f; } v; v.i = ((unsigned int)u) << 16; return v.f;
}
__device__ inline unsigned short f2bf(float f) {
  union { float f; unsigned int i; } v; v.f = f;
  unsigned int r = v.i + 0x7FFF + ((v.i >> 16) & 1);  // RNE
  return (unsigned short)(r >> 16);
}

// -------- k_cvtW: W transpose+convert to bf16; also zero-inits deg (kills memset node)
__global__ void k_cvtW(const float* __restrict__ W, unsigned short* __restrict__ Wt,
                       int* __restrict__ deg, int M) {
  int n = blockIdx.x, k = threadIdx.x;
  Wt[n * 256 + k] = f2bf(W[k * 256 + n]);
  for (int i = blockIdx.x * 256 + threadIdx.x; i < M; i += 256 * 256) deg[i] = 0;
}

// -------- k_fillgemm: block-specialized fusion of edge-bucket fill and projection.
// ROUND-13 BEST-KNOWN FORM (restored): blocks interleaved 1:2 (b%3==0 -> fill),
// A staged once to LDS (XOR-swizzled), B double-buffered via global_load_lds
// issued BEFORE compute. B-from-L2 variants (r14/r15) regressed ~17us: without
// the LDS pipeline + barrier pacing, per-k-step L2 latency is exposed.
__global__ __launch_bounds__(256, 2) void k_fillgemm(
    const float* __restrict__ feat, const unsigned short* __restrict__ Wt,
    const float* __restrict__ al, const float* __restrict__ ar,
    unsigned short* __restrict__ ftb, float* __restrict__ el,
    float* __restrict__ er, int M,
    const int* __restrict__ src, const int* __restrict__ dst,
    int* __restrict__ deg, int* __restrict__ bucket, int E)
{
  __shared__ unsigned short As[64 * 256];       // 32 KB: full A tile, bf16
  __shared__ unsigned short Bs[2][256 * 32];    // 2 x 16 KB
  const int t = threadIdx.x;
  const int b = blockIdx.x;
  const int q = b / 3, rmd = b % 3;

  if (rmd == 0) {
    // ---------------- fill path: edges [q*EPB, q*EPB+EPB) ----------------
    int e0 = q * EPB + t;
    #pragma unroll
    for (int j = 0; j < 8; ++j) {
      int e = e0 + j * 256;
      if (e < E) {
        int d = __builtin_nontemporal_load(dst + e);
        int s = __builtin_nontemporal_load(src + e);
        int p = atomicAdd(&deg[d], 1);
        bucket[(size_t)d * CAP + p] = s;
      }
    }
    return;
  }

  // ---------------- gemm path: block gi = b - q - 1 ----------------
  const int gi = b - q - 1;
  const int lane = t & 63;
  const int w = t >> 6;                 // wave index == head == col-block
  const int row0 = gi * 64;

  f32x4 acc[4][4] = {};

  // A prologue: 8 x 32B chunks per thread (NT loads), then cvt + swizzled ds_write.
  f32x4 av0[8], av1[8];
  #pragma unroll
  for (int j = 0; j < 8; ++j) {
    int g = j * 256 + t;
    int r = g >> 5, c = g & 31;
    const f32x4* ga = (const f32x4*)(feat + (size_t)min(row0 + r, M - 1) * KIN + c * 8);
    av0[j] = __builtin_nontemporal_load(ga);
    av1[j] = __builtin_nontemporal_load(ga + 1);
  }
  // B buffer 0 staged while A converts: 4 loads/thread cover 256 rows x 32 k
  const int bn0 = t >> 2, bkc = t & 3;
  #pragma unroll
  for (int j = 0; j < 4; ++j) {
    int n = j * 64 + bn0;
    const unsigned short* gb = Wt + n * 256 + ((bkc ^ ((n >> 1) & 3)) * 8);
    __builtin_amdgcn_global_load_lds(
        (const __attribute__((address_space(1))) void*)gb,
        (__attribute__((address_space(3))) void*)((char*)Bs[0] + j * 4096 + t * 16),
        16, 0, 0);
  }
  #pragma unroll
  for (int j = 0; j < 8; ++j) {
    int g = j * 256 + t;
    int r = g >> 5, c = g & 31;
    short8 pk;
    pk[0] = (short)f2bf(av0[j][0]); pk[1] = (short)f2bf(av0[j][1]);
    pk[2] = (short)f2bf(av0[j][2]); pk[3] = (short)f2bf(av0[j][3]);
    pk[4] = (short)f2bf(av1[j][0]); pk[5] = (short)f2bf(av1[j][1]);
    pk[6] = (short)f2bf(av1[j][2]); pk[7] = (short)f2bf(av1[j][3]);
    *(short8*)((char*)As + r * 512 + ((c ^ (r & 7)) * 16)) = pk;
  }
  __syncthreads();

  const int i = lane & 15, kc = lane >> 4;
  for (int kt = 0; kt < 8; ++kt) {
    if (kt < 7) {
      int k0 = (kt + 1) * 32;
      #pragma unroll
      for (int j = 0; j < 4; ++j) {
        int n = j * 64 + bn0;
        const unsigned short* gb = Wt + n * 256 + k0 + ((bkc ^ ((n >> 1) & 3)) * 8);
        __builtin_amdgcn_global_load_lds(
            (const __attribute__((address_space(1))) void*)gb,
            (__attribute__((address_space(3))) void*)((char*)Bs[(kt + 1) & 1] + j * 4096 + t * 16),
            16, 0, 0);
      }
    }
    short8 af[4], bf[4];
    #pragma unroll
    for (int m = 0; m < 4; ++m) {
      int r = m * 16 + i;
      int c = kt * 4 + kc;
      af[m] = *(const short8*)((const char*)As + r * 512 + ((c ^ (r & 7)) * 16));
    }
    const char* bbase = (const char*)Bs[kt & 1];
    #pragma unroll
    for (int n = 0; n < 4; ++n) {
      int nr = w * 64 + n * 16 + i;
      bf[n] = *(const short8*)(bbase + nr * 64 + ((kc ^ ((nr >> 1) & 3)) * 16));
    }
    #pragma unroll
    for (int m = 0; m < 4; ++m)
      #pragma unroll
      for (int n = 0; n < 4; ++n)
        acc[m][n] = __builtin_amdgcn_mfma_f32_16x16x32_bf16(af[m], bf[n], acc[m][n], 0, 0, 0);
    __syncthreads();   // drains vmcnt+lgkmcnt -> next B buffer ready
  }

  // epilogue: C/D layout col=lane&15, row=(lane>>4)*4+reg  [m89-verified]
  const int ci = lane & 15, rg = lane >> 4;
  #pragma unroll
  for (int m = 0; m < 4; ++m) {
    #pragma unroll
    for (int r = 0; r < 4; ++r) {
      int grow = row0 + m * 16 + rg * 4 + r;
      if (grow < M) {
        unsigned short* fp = ftb + (size_t)grow * NHID + w * 64;
        #pragma unroll
        for (int n = 0; n < 4; ++n) fp[n * 16 + ci] = f2bf(acc[m][n][r]);
      }
    }
  }
  float alv[4], arv[4];
  #pragma unroll
  for (int n = 0; n < 4; ++n) {
    alv[n] = al[w * DH + n * 16 + ci];
    arv[n] = ar[w * DH + n * 16 + ci];
  }
  #pragma unroll
  for (int m = 0; m < 4; ++m) {
    #pragma unroll
    for (int r = 0; r < 4; ++r) {
      float pl = 0.f, pr = 0.f;
      #pragma unroll
      for (int n = 0; n < 4; ++n) {
        pl += acc[m][n][r] * alv[n];
        pr += acc[m][n][r] * arv[n];
      }
      pl += __shfl_xor(pl, 1); pl += __shfl_xor(pl, 2);
      pl += __shfl_xor(pl, 4); pl += __shfl_xor(pl, 8);
      pr += __shfl_xor(pr, 1); pr += __shfl_xor(pr, 2);
      pr += __shfl_xor(pr, 4); pr += __shfl_xor(pr, 8);
      if (ci == 0) {
        int grow = row0 + m * 16 + rg * 4 + r;
        if (grow < M) { el[grow * HEADS + w] = pl; er[grow * HEADS + w] = pr; }
      }
    }
  }
}

// ---------------- Aggregation: wave per node, quarter-wave per edge ----------------
// Round-11 exact form. Serves 819 MB logical in ~136 us = 6.0 TB/s effective
// -- at the memory wall. Frozen.
__global__ __launch_bounds__(256) void k_aggr(
    const unsigned short* __restrict__ ftb, const float* __restrict__ el,
    const float* __restrict__ er, const int* __restrict__ deg,
    const int* __restrict__ bucket, float* __restrict__ out, int N)
{
  int n = blockIdx.x * 4 + (threadIdx.x >> 6);
  int lane = threadIdx.x & 63;
  if (n >= N) return;
  int q  = lane >> 4;          // edge slot 0..3
  int ql = lane & 15;          // dims ql*16 .. ql*16+15
  int hh = ql >> 2;            // head of my dims
  int start = n * CAP;
  int end = start + deg[n];
  const short8* ft8 = (const short8*)ftb;
  float acc[16] = {};
  float ws = 0.f;
  if (end > start) {
    float erh = er[n * HEADS + hh];
    int last = end - 1;
    int eA = start + q;
    int eB = eA + 4;
    int sB = bucket[min(eB, last)];
    {
      int sA = bucket[min(eA, last)];
      float lxA = el[sA * 4 + hh];
      short8 fa0 = ft8[(size_t)sA * 32 + ql * 2];
      short8 fa1 = ft8[(size_t)sA * 32 + ql * 2 + 1];
      for (int e0 = start; e0 < end; e0 += 4) {
        int sC = bucket[min(e0 + 8 + q, last)];
        float lxB = el[sB * 4 + hh];
        short8 fb0 = ft8[(size_t)sB * 32 + ql * 2];
        short8 fb1 = ft8[(size_t)sB * 32 + ql * 2 + 1];
        bool v = (e0 + q) < end;
        float x = lxA + erh;
        x = x > 0.f ? x : NEG_SLOPE * x;
        float ex = v ? __expf(x) : 0.f;
        ws += ex;
        #pragma unroll
        for (int j = 0; j < 8; ++j) acc[j]     += ex * bf2f((unsigned short)fa0[j]);
        #pragma unroll
        for (int j = 0; j < 8; ++j) acc[j + 8] += ex * bf2f((unsigned short)fa1[j]);
        sB = sC; lxA = lxB; fa0 = fb0; fa1 = fb1;
      }
    }
  }
  ws += __shfl_xor(ws, 16); ws += __shfl_xor(ws, 32);
  #pragma unroll
  for (int j = 0; j < 16; ++j) {
    acc[j] += __shfl_xor(acc[j], 16);
    acc[j] += __shfl_xor(acc[j], 32);
  }
  if (q == 0) {
    float inv = (end > start) ? 1.f / ws : 0.f;
    float* op = out + (size_t)n * NHID + ql * 16;
    #pragma unroll
    for (int j4 = 0; j4 < 4; ++j4)
      *(float4*)(op + j4 * 4) = make_float4(acc[j4 * 4] * inv, acc[j4 * 4 + 1] * inv,
                                            acc[j4 * 4 + 2] * inv, acc[j4 * 4 + 3] * inv);
  }
}

// ---------------- launch ----------------
extern "C" void kernel_launch(void* const* d_in, const int* in_sizes, int n_in,
                              void* d_out, int out_size, void* d_ws, size_t ws_size,
                              hipStream_t stream)
{
  const float* feat = (const float*)d_in[0];
  const float* W    = (const float*)d_in[1];
  const float* al   = (const float*)d_in[2];
  const float* ar   = (const float*)d_in[3];
  const int*   src  = (const int*)d_in[4];
  const int*   dst  = (const int*)d_in[5];
  const int M = in_sizes[0] / KIN;   // 100000
  const int E = in_sizes[4];         // 1600000
  float* out = (float*)d_out;

  char* base = (char*)d_ws;
  size_t off = 0;
  auto alloc = [&](size_t b) { char* p = base + off; off = (off + b + 255) & ~(size_t)255; return p; };
  unsigned short* ftb = (unsigned short*)alloc((size_t)M * NHID * sizeof(unsigned short)); // 51.2 MB
  unsigned short* Wt  = (unsigned short*)alloc(256 * 256 * sizeof(unsigned short));
  float* el     = (float*)alloc((size_t)M * HEADS * sizeof(float));
  float* er     = (float*)alloc((size_t)M * HEADS * sizeof(float));
  int*   deg    = (int*)alloc((size_t)M * sizeof(int));
  int*   bucket = (int*)alloc((size_t)M * CAP * sizeof(int));   // 51.2 MB
  (void)ws_size; (void)n_in; (void)out_size;

  k_cvtW<<<256, 256, 0, stream>>>(W, Wt, deg, M);
  int nF = (E + EPB - 1) / EPB;
  int nG = (M + 63) / 64;
  k_fillgemm<<<nF + nG, 256, 0, stream>>>(feat, Wt, al, ar, ftb, el, er, M,
                                          src, dst, deg, bucket, E);
  k_aggr<<<(M + 3) / 4, 256, 0, stream>>>(ftb, el, er, deg, bucket, out, M);
}